// Round 2
// baseline (250.985 us; speedup 1.0000x reference)
//
#include <hip/hip_runtime.h>
#include <hip/hip_bf16.h>

// Workspace layout:
//   [0, 128)          : float acc[B][4] = {num_pos, cls_sum, reg_sum, dist_sum} (B<=8)
//   [128, 128 + B*A)  : int8 state per anchor: -2 ignore, -1 negative, 0..C-1 positive class

__device__ __forceinline__ float wave_reduce_sum(float v) {
#pragma unroll
    for (int off = 32; off > 0; off >>= 1) v += __shfl_down(v, off);
    return v;
}

__device__ __forceinline__ float smooth_l1(float d) {
    // beta = 1/9: d<=beta ? 0.5*9*d^2 : d - 0.5/9
    return d <= (1.0f / 9.0f) ? 4.5f * d * d : d - (0.5f / 9.0f);
}

__global__ void zero_acc_kernel(float* __restrict__ acc) {
    if (threadIdx.x < 32) acc[threadIdx.x] = 0.0f;
}

__global__ __launch_bounds__(256) void phase1_kernel(
    const float* __restrict__ reg, const float* __restrict__ dist,
    const float* __restrict__ anchors, const float* __restrict__ ann,
    float* __restrict__ acc, signed char* __restrict__ state,
    int A, int C, int M) {
    const int b = blockIdx.y;
    __shared__ float s_ann[64 * 6];
    const float* annb = ann + (size_t)b * M * 6;
    for (int i = threadIdx.x; i < M * 6; i += blockDim.x) s_ann[i] = annb[i];
    __syncthreads();

    const int a = blockIdx.x * blockDim.x + threadIdx.x;
    float l_npos = 0.f, l_reg = 0.f, l_dist = 0.f;
    if (a < A) {
        const float4 av = *(const float4*)(anchors + (size_t)a * 4);
        const float aw = av.z - av.x, ah = av.w - av.y;
        const float acx = av.x + 0.5f * aw, acy = av.y + 0.5f * ah;
        const float aarea = aw * ah;

        float best = -1.0f;
        int bi = 0;
        for (int m = 0; m < M; ++m) {
            const float* g = s_ann + m * 6;
            float iou = -1.0f;
            if (g[4] != -1.0f) {
                float iw = fmaxf(fminf(av.z, g[2]) - fmaxf(av.x, g[0]), 0.f);
                float ih = fmaxf(fminf(av.w, g[3]) - fmaxf(av.y, g[1]), 0.f);
                float inter = iw * ih;
                float area = (g[2] - g[0]) * (g[3] - g[1]);
                float ua = fmaxf(aarea + area - inter, 1e-8f);
                iou = inter / ua;
            }
            if (iou > best) { best = iou; bi = m; }  // strict > => first max (jnp.argmax)
        }

        signed char st;
        if (best >= 0.5f) {
            const float* g = s_ann + bi * 6;
            st = (signed char)(int)g[4];
            l_npos = 1.f;
            // box regression targets
            const float4 rv = *(const float4*)(reg + ((size_t)b * A + a) * 4);
            const float gwr = g[2] - g[0], ghr = g[3] - g[1];
            const float gcx = g[0] + 0.5f * gwr, gcy = g[1] + 0.5f * ghr;
            const float gw = fmaxf(gwr, 1.f), gh = fmaxf(ghr, 1.f);
            const float t0 = ((gcx - acx) / aw) / 0.1f;
            const float t1 = ((gcy - acy) / ah) / 0.1f;
            const float t2 = __logf(gw / aw) / 0.2f;
            const float t3 = __logf(gh / ah) / 0.2f;
            l_reg = smooth_l1(fabsf(t0 - rv.x)) + smooth_l1(fabsf(t1 - rv.y)) +
                    smooth_l1(fabsf(t2 - rv.z)) + smooth_l1(fabsf(t3 - rv.w));
            // distance Huber (delta = 0.5)
            const float dv = dist[(size_t)b * A + a];
            const float dd = fabsf(dv - g[5]);
            l_dist = dd <= 0.5f ? 0.5f * dd * dd : 0.5f * (dd - 0.25f);
        } else if (best < 0.4f) {
            st = -1;
        } else {
            st = -2;
        }
        state[(size_t)b * A + a] = st;
    }

    // block reduce the three partial sums
    __shared__ float s_red[3][4];
    const float w0 = wave_reduce_sum(l_npos);
    const float w1 = wave_reduce_sum(l_reg);
    const float w2 = wave_reduce_sum(l_dist);
    const int lane = threadIdx.x & 63, wid = threadIdx.x >> 6;
    if (lane == 0) { s_red[0][wid] = w0; s_red[1][wid] = w1; s_red[2][wid] = w2; }
    __syncthreads();
    if (threadIdx.x == 0) {
        float t0 = 0.f, t1 = 0.f, t2 = 0.f;
#pragma unroll
        for (int i = 0; i < 4; ++i) { t0 += s_red[0][i]; t1 += s_red[1][i]; t2 += s_red[2][i]; }
        atomicAdd(&acc[b * 4 + 0], t0);
        atomicAdd(&acc[b * 4 + 2], t1);
        atomicAdd(&acc[b * 4 + 3], t2);
    }
}

__global__ __launch_bounds__(256) void phase2_kernel(
    const float* __restrict__ cls, const signed char* __restrict__ state,
    float* __restrict__ acc, int A, int C) {
    const int b = blockIdx.y;
    const int cpa = C >> 2;  // float4 chunks per anchor (C % 4 == 0)
    const float* __restrict__ clsb = cls + (size_t)b * A * C;
    const signed char* __restrict__ stb = state + (size_t)b * A;

    const long long stride = (long long)gridDim.x * blockDim.x;
    const long long idx0 = (long long)blockIdx.x * blockDim.x + threadIdx.x;
    int a = (int)(idx0 / cpa);
    int cc = (int)(idx0 % cpa);
    const int dA = (int)(stride / cpa);
    const int dC = (int)(stride % cpa);

    float lsum = 0.f;
    while (a < A) {
        const int st = stb[a];
        if (st != -2) {
            const int c0 = cc << 2;
            const float4 cv = *(const float4*)(clsb + (size_t)a * C + c0);
#pragma unroll
            for (int j = 0; j < 4; ++j) {
                float c = j == 0 ? cv.x : j == 1 ? cv.y : j == 2 ? cv.z : cv.w;
                c = fminf(fmaxf(c, 1e-4f), 1.0f - 1e-4f);
                const bool ispos = (st == c0 + j);
                const float om = 1.0f - c;
                const float x = ispos ? c : om;                       // log argument
                const float w = ispos ? 0.25f * om * om : 0.75f * c * c;  // focal weight
                lsum -= w * __logf(x);
            }
        }
        a += dA;
        cc += dC;
        if (cc >= cpa) { cc -= cpa; a += 1; }
    }

    const float v = wave_reduce_sum(lsum);
    __shared__ float s_red[4];
    const int lane = threadIdx.x & 63, wid = threadIdx.x >> 6;
    if (lane == 0) s_red[wid] = v;
    __syncthreads();
    if (threadIdx.x == 0) {
        atomicAdd(&acc[b * 4 + 1], s_red[0] + s_red[1] + s_red[2] + s_red[3]);
    }
}

__global__ void finalize_kernel(const float* __restrict__ acc, float* __restrict__ out, int B) {
    if (threadIdx.x == 0) {
        float cs = 0.f, rs = 0.f, ds = 0.f;
        for (int b = 0; b < B; ++b) {
            const float np_ = acc[b * 4 + 0];
            const float denom = fmaxf(np_, 1.f);
            cs += acc[b * 4 + 1] / denom;
            rs += np_ > 0.f ? acc[b * 4 + 2] / (denom * 4.f) : 0.f;
            ds += np_ > 0.f ? acc[b * 4 + 3] / denom : 0.f;
        }
        out[0] = cs / (float)B;
        out[1] = rs / (float)B;
        out[2] = ds / (float)B;
    }
}

extern "C" void kernel_launch(void* const* d_in, const int* in_sizes, int n_in,
                              void* d_out, int out_size, void* d_ws, size_t ws_size,
                              hipStream_t stream) {
    const float* cls     = (const float*)d_in[0];
    const float* reg     = (const float*)d_in[1];
    const float* dist    = (const float*)d_in[2];
    const float* anchors = (const float*)d_in[3];
    const float* ann     = (const float*)d_in[4];

    const int A = in_sizes[3] / 4;
    const int B = in_sizes[1] / (A * 4);
    const int C = in_sizes[0] / (B * A);
    const int M = in_sizes[4] / (B * 6);

    float* acc = (float*)d_ws;
    signed char* state = (signed char*)d_ws + 128;

    zero_acc_kernel<<<1, 64, 0, stream>>>(acc);

    dim3 b1(256), g1((A + 255) / 256, B);
    phase1_kernel<<<g1, b1, 0, stream>>>(reg, dist, anchors, ann, acc, state, A, C, M);

    dim3 b2(256), g2(1024, B);
    phase2_kernel<<<g2, b2, 0, stream>>>(cls, state, acc, A, C);

    finalize_kernel<<<1, 64, 0, stream>>>(acc, (float*)d_out, B);
}

// Round 3
// 92.202 us; speedup vs baseline: 2.7221x; 2.7221x over previous
//
#include <hip/hip_runtime.h>
#include <hip/hip_bf16.h>

// Workspace layout:
//   [0, B*nb*16) : float4 per-block partials {num_pos, cls_sum, reg_sum, dist_sum}
// 2 kernels: fused (assignment + focal sweep, per-block partials), finalize.

__device__ __forceinline__ float wave_reduce_sum(float v) {
#pragma unroll
    for (int off = 32; off > 0; off >>= 1) v += __shfl_down(v, off);
    return v;
}

__device__ __forceinline__ float smooth_l1(float d) {
    // beta = 1/9: d<=beta ? 0.5*9*d^2 : d - 0.5/9
    return d <= (1.0f / 9.0f) ? 4.5f * d * d : d - (0.5f / 9.0f);
}

template <int CPA>  // chunks (float4) per anchor = C/4, compile-time
__global__ __launch_bounds__(256) void fused_kernel(
    const float* __restrict__ cls, const float* __restrict__ reg,
    const float* __restrict__ dist, const float* __restrict__ anchors,
    const float* __restrict__ ann, float4* __restrict__ partials,
    int A, int M, int nb) {
    const int b = blockIdx.y;
    const int base = blockIdx.x << 8;  // 256 anchors per block
    const int tid = threadIdx.x;

    __shared__ float s_ann[64 * 6];
    __shared__ signed char s_state[256];
    const float* annb = ann + (size_t)b * M * 6;
    for (int i = tid; i < M * 6; i += 256) s_ann[i] = annb[i];
    s_state[tid] = -2;  // default: ignore (also covers a >= A tail)
    __syncthreads();

    // ---- phase 1: anchor assignment ----
    const int a = base + tid;
    float l_npos = 0.f, l_reg = 0.f, l_dist = 0.f;
    if (a < A) {
        const float4 av = *(const float4*)(anchors + (size_t)a * 4);
        const float aw = av.z - av.x, ah = av.w - av.y;
        const float acx = av.x + 0.5f * aw, acy = av.y + 0.5f * ah;
        const float aarea = aw * ah;

        float best = -1.0f;
        int bi = 0;
        for (int m = 0; m < M; ++m) {
            const float* g = s_ann + m * 6;
            float iou = -1.0f;
            if (g[4] != -1.0f) {
                float iw = fmaxf(fminf(av.z, g[2]) - fmaxf(av.x, g[0]), 0.f);
                float ih = fmaxf(fminf(av.w, g[3]) - fmaxf(av.y, g[1]), 0.f);
                float inter = iw * ih;
                float area = (g[2] - g[0]) * (g[3] - g[1]);
                float ua = fmaxf(aarea + area - inter, 1e-8f);
                iou = inter / ua;
            }
            if (iou > best) { best = iou; bi = m; }  // strict > => first max (jnp.argmax)
        }

        signed char st;
        if (best >= 0.5f) {
            const float* g = s_ann + bi * 6;
            st = (signed char)(int)g[4];
            l_npos = 1.f;
            const float4 rv = *(const float4*)(reg + ((size_t)b * A + a) * 4);
            const float gwr = g[2] - g[0], ghr = g[3] - g[1];
            const float gcx = g[0] + 0.5f * gwr, gcy = g[1] + 0.5f * ghr;
            const float gw = fmaxf(gwr, 1.f), gh = fmaxf(ghr, 1.f);
            const float t0 = ((gcx - acx) / aw) / 0.1f;
            const float t1 = ((gcy - acy) / ah) / 0.1f;
            const float t2 = __logf(gw / aw) / 0.2f;
            const float t3 = __logf(gh / ah) / 0.2f;
            l_reg = smooth_l1(fabsf(t0 - rv.x)) + smooth_l1(fabsf(t1 - rv.y)) +
                    smooth_l1(fabsf(t2 - rv.z)) + smooth_l1(fabsf(t3 - rv.w));
            const float dv = dist[(size_t)b * A + a];
            const float dd = fabsf(dv - g[5]);
            l_dist = dd <= 0.5f ? 0.5f * dd * dd : 0.5f * (dd - 0.25f);
        } else if (best < 0.4f) {
            st = -1;
        } else {
            st = -2;
        }
        s_state[tid] = st;
    }
    __syncthreads();

    // ---- phase 2: focal loss over this block's 256 anchors' cls rows ----
    const float4* __restrict__ clsb =
        (const float4*)(cls + ((size_t)b * A + base) * (CPA * 4));
    int a_local = tid / CPA;
    int cc = tid % CPA;
    constexpr int dA = 256 / CPA;
    constexpr int dC = 256 % CPA;
    float lsum = 0.f;
#pragma unroll 4
    for (int k = 0; k < CPA; ++k) {
        const int st = s_state[a_local];
        if (st != -2) {
            const float4 cv = clsb[k * 256 + tid];
            const int c0 = cc << 2;
#pragma unroll
            for (int j = 0; j < 4; ++j) {
                float c = j == 0 ? cv.x : j == 1 ? cv.y : j == 2 ? cv.z : cv.w;
                c = fminf(fmaxf(c, 1e-4f), 1.0f - 1e-4f);
                const bool ispos = (st == c0 + j);
                const float om = 1.0f - c;
                const float x = ispos ? c : om;                           // log arg
                const float w = ispos ? 0.25f * om * om : 0.75f * c * c;  // focal weight
                lsum -= w * __logf(x);
            }
        }
        a_local += dA;
        cc += dC;
        if (cc >= CPA) { cc -= CPA; ++a_local; }
    }

    // ---- block reduce 4 sums -> one float4 partial per block ----
    __shared__ float s_red[4][4];
    const float w0 = wave_reduce_sum(l_npos);
    const float w1 = wave_reduce_sum(lsum);
    const float w2 = wave_reduce_sum(l_reg);
    const float w3 = wave_reduce_sum(l_dist);
    const int lane = tid & 63, wid = tid >> 6;
    if (lane == 0) {
        s_red[0][wid] = w0; s_red[1][wid] = w1; s_red[2][wid] = w2; s_red[3][wid] = w3;
    }
    __syncthreads();
    if (tid == 0) {
        float4 p;
        p.x = s_red[0][0] + s_red[0][1] + s_red[0][2] + s_red[0][3];
        p.y = s_red[1][0] + s_red[1][1] + s_red[1][2] + s_red[1][3];
        p.z = s_red[2][0] + s_red[2][1] + s_red[2][2] + s_red[2][3];
        p.w = s_red[3][0] + s_red[3][1] + s_red[3][2] + s_red[3][3];
        partials[(size_t)b * nb + blockIdx.x] = p;
    }
}

// One wave per batch sample; B <= 8.
__global__ void finalize_kernel(const float4* __restrict__ partials,
                                float* __restrict__ out, int B, int nb) {
    const int lane = threadIdx.x & 63;
    const int b = threadIdx.x >> 6;
    __shared__ float s_res[8][3];
    if (b < B) {
        float np_ = 0.f, cs = 0.f, rs = 0.f, ds = 0.f;
        for (int i = lane; i < nb; i += 64) {
            const float4 p = partials[(size_t)b * nb + i];
            np_ += p.x; cs += p.y; rs += p.z; ds += p.w;
        }
        np_ = wave_reduce_sum(np_);
        cs = wave_reduce_sum(cs);
        rs = wave_reduce_sum(rs);
        ds = wave_reduce_sum(ds);
        if (lane == 0) {
            const float denom = fmaxf(np_, 1.f);
            s_res[b][0] = cs / denom;
            s_res[b][1] = np_ > 0.f ? rs / (denom * 4.f) : 0.f;
            s_res[b][2] = np_ > 0.f ? ds / denom : 0.f;
        }
    }
    __syncthreads();
    if (threadIdx.x == 0) {
        float c = 0.f, r = 0.f, d = 0.f;
        for (int i = 0; i < B; ++i) { c += s_res[i][0]; r += s_res[i][1]; d += s_res[i][2]; }
        out[0] = c / (float)B;
        out[1] = r / (float)B;
        out[2] = d / (float)B;
    }
}

// Generic fallback for C != 80 (runtime chunks-per-anchor).
__global__ __launch_bounds__(256) void fused_generic_kernel(
    const float* __restrict__ cls, const float* __restrict__ reg,
    const float* __restrict__ dist, const float* __restrict__ anchors,
    const float* __restrict__ ann, float4* __restrict__ partials,
    int A, int C, int M, int nb) {
    const int b = blockIdx.y;
    const int base = blockIdx.x << 8;
    const int tid = threadIdx.x;
    const int cpa = C >> 2;

    __shared__ float s_ann[64 * 6];
    __shared__ signed char s_state[256];
    const float* annb = ann + (size_t)b * M * 6;
    for (int i = tid; i < M * 6; i += 256) s_ann[i] = annb[i];
    s_state[tid] = -2;
    __syncthreads();

    const int a = base + tid;
    float l_npos = 0.f, l_reg = 0.f, l_dist = 0.f;
    if (a < A) {
        const float4 av = *(const float4*)(anchors + (size_t)a * 4);
        const float aw = av.z - av.x, ah = av.w - av.y;
        const float acx = av.x + 0.5f * aw, acy = av.y + 0.5f * ah;
        const float aarea = aw * ah;
        float best = -1.0f;
        int bi = 0;
        for (int m = 0; m < M; ++m) {
            const float* g = s_ann + m * 6;
            float iou = -1.0f;
            if (g[4] != -1.0f) {
                float iw = fmaxf(fminf(av.z, g[2]) - fmaxf(av.x, g[0]), 0.f);
                float ih = fmaxf(fminf(av.w, g[3]) - fmaxf(av.y, g[1]), 0.f);
                float inter = iw * ih;
                float area = (g[2] - g[0]) * (g[3] - g[1]);
                float ua = fmaxf(aarea + area - inter, 1e-8f);
                iou = inter / ua;
            }
            if (iou > best) { best = iou; bi = m; }
        }
        signed char st;
        if (best >= 0.5f) {
            const float* g = s_ann + bi * 6;
            st = (signed char)(int)g[4];
            l_npos = 1.f;
            const float4 rv = *(const float4*)(reg + ((size_t)b * A + a) * 4);
            const float gwr = g[2] - g[0], ghr = g[3] - g[1];
            const float gcx = g[0] + 0.5f * gwr, gcy = g[1] + 0.5f * ghr;
            const float gw = fmaxf(gwr, 1.f), gh = fmaxf(ghr, 1.f);
            const float t0 = ((gcx - acx) / aw) / 0.1f;
            const float t1 = ((gcy - acy) / ah) / 0.1f;
            const float t2 = __logf(gw / aw) / 0.2f;
            const float t3 = __logf(gh / ah) / 0.2f;
            l_reg = smooth_l1(fabsf(t0 - rv.x)) + smooth_l1(fabsf(t1 - rv.y)) +
                    smooth_l1(fabsf(t2 - rv.z)) + smooth_l1(fabsf(t3 - rv.w));
            const float dv = dist[(size_t)b * A + a];
            const float dd = fabsf(dv - g[5]);
            l_dist = dd <= 0.5f ? 0.5f * dd * dd : 0.5f * (dd - 0.25f);
        } else if (best < 0.4f) {
            st = -1;
        } else {
            st = -2;
        }
        s_state[tid] = st;
    }
    __syncthreads();

    const float4* __restrict__ clsb = (const float4*)(cls + ((size_t)b * A + base) * C);
    int a_local = tid / cpa;
    int cc = tid % cpa;
    const int dA = 256 / cpa;
    const int dC = 256 % cpa;
    float lsum = 0.f;
    for (int k = 0; k < cpa; ++k) {
        const int st = s_state[a_local];
        if (st != -2) {
            const float4 cv = clsb[k * 256 + tid];
            const int c0 = cc << 2;
#pragma unroll
            for (int j = 0; j < 4; ++j) {
                float c = j == 0 ? cv.x : j == 1 ? cv.y : j == 2 ? cv.z : cv.w;
                c = fminf(fmaxf(c, 1e-4f), 1.0f - 1e-4f);
                const bool ispos = (st == c0 + j);
                const float om = 1.0f - c;
                const float x = ispos ? c : om;
                const float w = ispos ? 0.25f * om * om : 0.75f * c * c;
                lsum -= w * __logf(x);
            }
        }
        a_local += dA;
        cc += dC;
        if (cc >= cpa) { cc -= cpa; ++a_local; }
    }

    __shared__ float s_red[4][4];
    const float w0 = wave_reduce_sum(l_npos);
    const float w1 = wave_reduce_sum(lsum);
    const float w2 = wave_reduce_sum(l_reg);
    const float w3 = wave_reduce_sum(l_dist);
    const int lane = tid & 63, wid = tid >> 6;
    if (lane == 0) {
        s_red[0][wid] = w0; s_red[1][wid] = w1; s_red[2][wid] = w2; s_red[3][wid] = w3;
    }
    __syncthreads();
    if (tid == 0) {
        float4 p;
        p.x = s_red[0][0] + s_red[0][1] + s_red[0][2] + s_red[0][3];
        p.y = s_red[1][0] + s_red[1][1] + s_red[1][2] + s_red[1][3];
        p.z = s_red[2][0] + s_red[2][1] + s_red[2][2] + s_red[2][3];
        p.w = s_red[3][0] + s_red[3][1] + s_red[3][2] + s_red[3][3];
        partials[(size_t)b * nb + blockIdx.x] = p;
    }
}

extern "C" void kernel_launch(void* const* d_in, const int* in_sizes, int n_in,
                              void* d_out, int out_size, void* d_ws, size_t ws_size,
                              hipStream_t stream) {
    const float* cls     = (const float*)d_in[0];
    const float* reg     = (const float*)d_in[1];
    const float* dist    = (const float*)d_in[2];
    const float* anchors = (const float*)d_in[3];
    const float* ann     = (const float*)d_in[4];

    const int A = in_sizes[3] / 4;
    const int B = in_sizes[1] / (A * 4);
    const int C = in_sizes[0] / (B * A);
    const int M = in_sizes[4] / (B * 6);
    const int nb = (A + 255) / 256;

    float4* partials = (float4*)d_ws;

    dim3 g(nb, B), blk(256);
    if (C == 80) {
        fused_kernel<20><<<g, blk, 0, stream>>>(cls, reg, dist, anchors, ann,
                                                partials, A, M, nb);
    } else {
        fused_generic_kernel<<<g, blk, 0, stream>>>(cls, reg, dist, anchors, ann,
                                                    partials, A, C, M, nb);
    }
    finalize_kernel<<<1, B * 64, 0, stream>>>(partials, (float*)d_out, B, nb);
}

// Round 4
// 84.129 us; speedup vs baseline: 2.9834x; 1.0960x over previous
//
#include <hip/hip_runtime.h>
#include <hip/hip_bf16.h>

// Workspace layout:
//   [0, B*nb*16) : float4 per-block partials {num_pos, cls_sum, reg_sum, dist_sum}
// fused kernel: branch-free streaming focal sum + assignment + rare corrections.

typedef float v4f __attribute__((ext_vector_type(4)));

#define LN2_075 0.51986038542f  // 0.75 * ln(2)

__device__ __forceinline__ float wave_reduce_sum(float v) {
#pragma unroll
    for (int off = 32; off > 0; off >>= 1) v += __shfl_down(v, off);
    return v;
}

__device__ __forceinline__ float smooth_l1(float d) {
    // beta = 1/9: d<=beta ? 0.5*9*d^2 : d - 0.5/9
    return d <= (1.0f / 9.0f) ? 4.5f * d * d : d - (0.5f / 9.0f);
}

template <int CPA>  // chunks (float4) per anchor = C/4, compile-time
__global__ __launch_bounds__(256) void fused_kernel(
    const float* __restrict__ cls, const float* __restrict__ reg,
    const float* __restrict__ dist, const float* __restrict__ anchors,
    const float* __restrict__ ann, float4* __restrict__ partials,
    int A, int M, int nb) {
    const int b = blockIdx.y;
    const int base = blockIdx.x << 8;  // 256 anchors per block
    const int tid = threadIdx.x;
    const int lane = tid & 63;

    __shared__ float s_ann[64 * 6];
    const float* annb = ann + (size_t)b * M * 6;
    for (int i = tid; i < M * 6; i += 256) s_ann[i] = annb[i];

    // ---- streaming pass: treat EVERY element as a negative target ----
    // loss_elem = 0.75*c^2*(-log(1-c));  accumulate c^2*log2(1-c), scale once.
    const v4f* __restrict__ clsb = (const v4f*)(cls + ((size_t)b * A + base) * (CPA * 4));
    float acc2 = 0.f;
    if (base + 256 <= A) {
#pragma unroll
        for (int k = 0; k < CPA; ++k) {
            const v4f cv = __builtin_nontemporal_load(&clsb[k * 256 + tid]);
#pragma unroll
            for (int j = 0; j < 4; ++j) {
                const float c = fminf(fmaxf(cv[j], 1e-4f), 1.0f - 1e-4f);
                acc2 = fmaf(c * c, __log2f(1.0f - c), acc2);
            }
        }
    } else {
        const int nch = (A - base) * CPA;
        for (int k = 0; k < CPA; ++k) {
            const int idx = k * 256 + tid;
            if (idx < nch) {
                const v4f cv = __builtin_nontemporal_load(&clsb[idx]);
#pragma unroll
                for (int j = 0; j < 4; ++j) {
                    const float c = fminf(fmaxf(cv[j], 1e-4f), 1.0f - 1e-4f);
                    acc2 = fmaf(c * c, __log2f(1.0f - c), acc2);
                }
            }
        }
    }

    __syncthreads();  // s_ann ready

    // ---- phase 1: anchor assignment (registers only) ----
    const int a = base + tid;
    float l_npos = 0.f, l_reg = 0.f, l_dist = 0.f;
    int st = -1;  // -1 negative (incl. tail), -2 ignore, >=0 positive class
    if (a < A) {
        const float4 av = *(const float4*)(anchors + (size_t)a * 4);
        const float aw = av.z - av.x, ah = av.w - av.y;
        const float acx = av.x + 0.5f * aw, acy = av.y + 0.5f * ah;
        const float aarea = aw * ah;

        float best = -1.0f;
        int bi = 0;
        for (int m = 0; m < M; ++m) {
            const float* g = s_ann + m * 6;
            float iou = -1.0f;
            if (g[4] != -1.0f) {
                float iw = fmaxf(fminf(av.z, g[2]) - fmaxf(av.x, g[0]), 0.f);
                float ih = fmaxf(fminf(av.w, g[3]) - fmaxf(av.y, g[1]), 0.f);
                float inter = iw * ih;
                float area = (g[2] - g[0]) * (g[3] - g[1]);
                float ua = fmaxf(aarea + area - inter, 1e-8f);
                iou = inter / ua;
            }
            if (iou > best) { best = iou; bi = m; }  // strict > => first max (jnp.argmax)
        }

        if (best >= 0.5f) {
            const float* g = s_ann + bi * 6;
            st = (int)g[4];
            l_npos = 1.f;
            const float4 rv = *(const float4*)(reg + ((size_t)b * A + a) * 4);
            const float gwr = g[2] - g[0], ghr = g[3] - g[1];
            const float gcx = g[0] + 0.5f * gwr, gcy = g[1] + 0.5f * ghr;
            const float gw = fmaxf(gwr, 1.f), gh = fmaxf(ghr, 1.f);
            const float t0 = ((gcx - acx) / aw) / 0.1f;
            const float t1 = ((gcy - acy) / ah) / 0.1f;
            const float t2 = __logf(gw / aw) / 0.2f;
            const float t3 = __logf(gh / ah) / 0.2f;
            l_reg = smooth_l1(fabsf(t0 - rv.x)) + smooth_l1(fabsf(t1 - rv.y)) +
                    smooth_l1(fabsf(t2 - rv.z)) + smooth_l1(fabsf(t3 - rv.w));
            const float dv = dist[(size_t)b * A + a];
            const float dd = fabsf(dv - g[5]);
            l_dist = dd <= 0.5f ? 0.5f * dd * dd : 0.5f * (dd - 0.25f);
        } else if (best >= 0.4f) {
            st = -2;
        }
    }

    // ---- corrections for rare non-negative anchors (wave-cooperative) ----
    float corr = 0.f;
    unsigned long long mask = __ballot(st != -1);
    const int wbase = tid & ~63;
    while (mask) {
        const int bit = (int)__ffsll(mask) - 1;
        mask &= mask - 1;
        const int sst = __shfl(st, bit);
        const int la = wbase + bit;  // local anchor index within block
        if (sst == -2) {
            // ignored anchor: remove its entire streamed row
            float part = 0.f;
            if (lane < CPA) {
                const v4f cv = clsb[(size_t)la * CPA + lane];
#pragma unroll
                for (int j = 0; j < 4; ++j) {
                    const float c = fminf(fmaxf(cv[j], 1e-4f), 1.0f - 1e-4f);
                    part = fmaf(c * c, __log2f(1.0f - c), part);
                }
            }
            part = wave_reduce_sum(part);
            if (lane == 0) corr += LN2_075 * part;  // minus streamed (streamed scale is -LN2_075)
        } else if (lane == 0) {
            // positive anchor: swap its labeled element from neg-form to pos-form
            const float cr = cls[((size_t)b * A + base + la) * (CPA * 4) + sst];
            const float c = fminf(fmaxf(cr, 1e-4f), 1.0f - 1e-4f);
            const float om = 1.0f - c;
            corr += LN2_075 * (c * c * __log2f(om))   // remove streamed negative term
                    + 0.25f * om * om * (-__logf(c)); // add focal positive term
        }
    }

    const float lsum = fmaf(acc2, -LN2_075, corr);

    // ---- block reduce 4 sums -> one float4 partial per block ----
    __shared__ float s_red[4][4];
    const float w0 = wave_reduce_sum(l_npos);
    const float w1 = wave_reduce_sum(lsum);
    const float w2 = wave_reduce_sum(l_reg);
    const float w3 = wave_reduce_sum(l_dist);
    const int wid = tid >> 6;
    if (lane == 0) {
        s_red[0][wid] = w0; s_red[1][wid] = w1; s_red[2][wid] = w2; s_red[3][wid] = w3;
    }
    __syncthreads();
    if (tid == 0) {
        float4 p;
        p.x = s_red[0][0] + s_red[0][1] + s_red[0][2] + s_red[0][3];
        p.y = s_red[1][0] + s_red[1][1] + s_red[1][2] + s_red[1][3];
        p.z = s_red[2][0] + s_red[2][1] + s_red[2][2] + s_red[2][3];
        p.w = s_red[3][0] + s_red[3][1] + s_red[3][2] + s_red[3][3];
        partials[(size_t)b * nb + blockIdx.x] = p;
    }
}

// One wave per batch sample; B <= 8.
__global__ void finalize_kernel(const float4* __restrict__ partials,
                                float* __restrict__ out, int B, int nb) {
    const int lane = threadIdx.x & 63;
    const int b = threadIdx.x >> 6;
    __shared__ float s_res[8][3];
    if (b < B) {
        float np_ = 0.f, cs = 0.f, rs = 0.f, ds = 0.f;
        for (int i = lane; i < nb; i += 64) {
            const float4 p = partials[(size_t)b * nb + i];
            np_ += p.x; cs += p.y; rs += p.z; ds += p.w;
        }
        np_ = wave_reduce_sum(np_);
        cs = wave_reduce_sum(cs);
        rs = wave_reduce_sum(rs);
        ds = wave_reduce_sum(ds);
        if (lane == 0) {
            const float denom = fmaxf(np_, 1.f);
            s_res[b][0] = cs / denom;
            s_res[b][1] = np_ > 0.f ? rs / (denom * 4.f) : 0.f;
            s_res[b][2] = np_ > 0.f ? ds / denom : 0.f;
        }
    }
    __syncthreads();
    if (threadIdx.x == 0) {
        float c = 0.f, r = 0.f, d = 0.f;
        for (int i = 0; i < B; ++i) { c += s_res[i][0]; r += s_res[i][1]; d += s_res[i][2]; }
        out[0] = c / (float)B;
        out[1] = r / (float)B;
        out[2] = d / (float)B;
    }
}

// Generic fallback for C != 80 (runtime chunks-per-anchor).
__global__ __launch_bounds__(256) void fused_generic_kernel(
    const float* __restrict__ cls, const float* __restrict__ reg,
    const float* __restrict__ dist, const float* __restrict__ anchors,
    const float* __restrict__ ann, float4* __restrict__ partials,
    int A, int C, int M, int nb) {
    const int b = blockIdx.y;
    const int base = blockIdx.x << 8;
    const int tid = threadIdx.x;
    const int cpa = C >> 2;

    __shared__ float s_ann[64 * 6];
    __shared__ signed char s_state[256];
    const float* annb = ann + (size_t)b * M * 6;
    for (int i = tid; i < M * 6; i += 256) s_ann[i] = annb[i];
    s_state[tid] = -2;
    __syncthreads();

    const int a = base + tid;
    float l_npos = 0.f, l_reg = 0.f, l_dist = 0.f;
    if (a < A) {
        const float4 av = *(const float4*)(anchors + (size_t)a * 4);
        const float aw = av.z - av.x, ah = av.w - av.y;
        const float acx = av.x + 0.5f * aw, acy = av.y + 0.5f * ah;
        const float aarea = aw * ah;
        float best = -1.0f;
        int bi = 0;
        for (int m = 0; m < M; ++m) {
            const float* g = s_ann + m * 6;
            float iou = -1.0f;
            if (g[4] != -1.0f) {
                float iw = fmaxf(fminf(av.z, g[2]) - fmaxf(av.x, g[0]), 0.f);
                float ih = fmaxf(fminf(av.w, g[3]) - fmaxf(av.y, g[1]), 0.f);
                float inter = iw * ih;
                float area = (g[2] - g[0]) * (g[3] - g[1]);
                float ua = fmaxf(aarea + area - inter, 1e-8f);
                iou = inter / ua;
            }
            if (iou > best) { best = iou; bi = m; }
        }
        signed char st;
        if (best >= 0.5f) {
            const float* g = s_ann + bi * 6;
            st = (signed char)(int)g[4];
            l_npos = 1.f;
            const float4 rv = *(const float4*)(reg + ((size_t)b * A + a) * 4);
            const float gwr = g[2] - g[0], ghr = g[3] - g[1];
            const float gcx = g[0] + 0.5f * gwr, gcy = g[1] + 0.5f * ghr;
            const float gw = fmaxf(gwr, 1.f), gh = fmaxf(ghr, 1.f);
            const float t0 = ((gcx - acx) / aw) / 0.1f;
            const float t1 = ((gcy - acy) / ah) / 0.1f;
            const float t2 = __logf(gw / aw) / 0.2f;
            const float t3 = __logf(gh / ah) / 0.2f;
            l_reg = smooth_l1(fabsf(t0 - rv.x)) + smooth_l1(fabsf(t1 - rv.y)) +
                    smooth_l1(fabsf(t2 - rv.z)) + smooth_l1(fabsf(t3 - rv.w));
            const float dv = dist[(size_t)b * A + a];
            const float dd = fabsf(dv - g[5]);
            l_dist = dd <= 0.5f ? 0.5f * dd * dd : 0.5f * (dd - 0.25f);
        } else if (best < 0.4f) {
            st = -1;
        } else {
            st = -2;
        }
        s_state[tid] = st;
    }
    __syncthreads();

    const float4* __restrict__ clsb = (const float4*)(cls + ((size_t)b * A + base) * C);
    int a_local = tid / cpa;
    int cc = tid % cpa;
    const int dA = 256 / cpa;
    const int dC = 256 % cpa;
    float lsum = 0.f;
    for (int k = 0; k < cpa; ++k) {
        const int st = s_state[a_local];
        if (st != -2) {
            const float4 cv = clsb[k * 256 + tid];
            const int c0 = cc << 2;
#pragma unroll
            for (int j = 0; j < 4; ++j) {
                float c = j == 0 ? cv.x : j == 1 ? cv.y : j == 2 ? cv.z : cv.w;
                c = fminf(fmaxf(c, 1e-4f), 1.0f - 1e-4f);
                const bool ispos = (st == c0 + j);
                const float om = 1.0f - c;
                const float x = ispos ? c : om;
                const float w = ispos ? 0.25f * om * om : 0.75f * c * c;
                lsum -= w * __logf(x);
            }
        }
        a_local += dA;
        cc += dC;
        if (cc >= cpa) { cc -= cpa; ++a_local; }
    }

    __shared__ float s_red[4][4];
    const float w0 = wave_reduce_sum(l_npos);
    const float w1 = wave_reduce_sum(lsum);
    const float w2 = wave_reduce_sum(l_reg);
    const float w3 = wave_reduce_sum(l_dist);
    const int lane = tid & 63, wid = tid >> 6;
    if (lane == 0) {
        s_red[0][wid] = w0; s_red[1][wid] = w1; s_red[2][wid] = w2; s_red[3][wid] = w3;
    }
    __syncthreads();
    if (tid == 0) {
        float4 p;
        p.x = s_red[0][0] + s_red[0][1] + s_red[0][2] + s_red[0][3];
        p.y = s_red[1][0] + s_red[1][1] + s_red[1][2] + s_red[1][3];
        p.z = s_red[2][0] + s_red[2][1] + s_red[2][2] + s_red[2][3];
        p.w = s_red[3][0] + s_red[3][1] + s_red[3][2] + s_red[3][3];
        partials[(size_t)b * nb + blockIdx.x] = p;
    }
}

extern "C" void kernel_launch(void* const* d_in, const int* in_sizes, int n_in,
                              void* d_out, int out_size, void* d_ws, size_t ws_size,
                              hipStream_t stream) {
    const float* cls     = (const float*)d_in[0];
    const float* reg     = (const float*)d_in[1];
    const float* dist    = (const float*)d_in[2];
    const float* anchors = (const float*)d_in[3];
    const float* ann     = (const float*)d_in[4];

    const int A = in_sizes[3] / 4;
    const int B = in_sizes[1] / (A * 4);
    const int C = in_sizes[0] / (B * A);
    const int M = in_sizes[4] / (B * 6);
    const int nb = (A + 255) / 256;

    float4* partials = (float4*)d_ws;

    dim3 g(nb, B), blk(256);
    if (C == 80) {
        fused_kernel<20><<<g, blk, 0, stream>>>(cls, reg, dist, anchors, ann,
                                                partials, A, M, nb);
    } else {
        fused_generic_kernel<<<g, blk, 0, stream>>>(cls, reg, dist, anchors, ann,
                                                    partials, A, C, M, nb);
    }
    finalize_kernel<<<1, B * 64, 0, stream>>>(partials, (float*)d_out, B, nb);
}

// Round 5
// 79.433 us; speedup vs baseline: 3.1597x; 1.0591x over previous
//
#include <hip/hip_runtime.h>
#include <hip/hip_bf16.h>

// Workspace layout:
//   [0, 8192)        : float partA[B][SBLK]   per-stream-block cls partial sums
//   [8192, 8192+60KB): float4 partB[B][nb]    per-assign-block {npos, corr, reg, dist}
// main kernel: blockIdx.x < SBLK  -> pure streaming reduction over cls (all-negative form)
//              blockIdx.x >= SBLK -> anchor assignment + rare corrections
// finalize: merge partials, write 3 outputs.

typedef float v4f __attribute__((ext_vector_type(4)));

#define LN2_075 0.51986038542f  // 0.75 * ln(2)

__device__ __forceinline__ float wave_reduce_sum(float v) {
#pragma unroll
    for (int off = 32; off > 0; off >>= 1) v += __shfl_down(v, off);
    return v;
}

__device__ __forceinline__ float smooth_l1(float d) {
    // beta = 1/9: d<=beta ? 0.5*9*d^2 : d - 0.5/9
    return d <= (1.0f / 9.0f) ? 4.5f * d * d : d - (0.5f / 9.0f);
}

__device__ __forceinline__ float proc4(v4f cv, float acc) {
#pragma unroll
    for (int j = 0; j < 4; ++j) {
        const float c = fminf(fmaxf(cv[j], 1e-4f), 1.0f - 1e-4f);
        acc = fmaf(c * c, __log2f(1.0f - c), acc);
    }
    return acc;
}

template <int CPA>  // float4 chunks per anchor = C/4
__global__ __launch_bounds__(256) void main_kernel(
    const float* __restrict__ cls, const float* __restrict__ reg,
    const float* __restrict__ dist, const float* __restrict__ anchors,
    const float* __restrict__ ann, float* __restrict__ partA,
    float4* __restrict__ partB, int A, int M, int SBLK, int nb) {
    const int b = blockIdx.y;
    const int tid = threadIdx.x;
    const int lane = tid & 63;
    const int wid = tid >> 6;

    if (blockIdx.x < SBLK) {
        // ================= STREAM ROLE: pure read-reduction =================
        const int NC4 = A * CPA;  // float4s per sample
        const v4f* __restrict__ p = (const v4f*)(cls + (size_t)b * NC4 * 4);
        const int s = SBLK << 8;
        int i = (blockIdx.x << 8) + tid;
        float acc = 0.f;
        for (; i + 3 * s < NC4; i += 4 * s) {
            const v4f a0 = __builtin_nontemporal_load(&p[i]);
            const v4f a1 = __builtin_nontemporal_load(&p[i + s]);
            const v4f a2 = __builtin_nontemporal_load(&p[i + 2 * s]);
            const v4f a3 = __builtin_nontemporal_load(&p[i + 3 * s]);
            acc = proc4(a0, acc);
            acc = proc4(a1, acc);
            acc = proc4(a2, acc);
            acc = proc4(a3, acc);
        }
        for (; i < NC4; i += s) acc = proc4(__builtin_nontemporal_load(&p[i]), acc);

        __shared__ float s_red[4];
        acc = wave_reduce_sum(acc);
        if (lane == 0) s_red[wid] = acc;
        __syncthreads();
        if (tid == 0)
            partA[(size_t)b * SBLK + blockIdx.x] = s_red[0] + s_red[1] + s_red[2] + s_red[3];
        return;
    }

    // ================= ASSIGN ROLE: IoU assignment + corrections =================
    const int blk = blockIdx.x - SBLK;
    const int base = blk << 8;  // 256 anchors per block

    __shared__ float s_ann[64 * 6];
    const float* annb = ann + (size_t)b * M * 6;
    for (int i = tid; i < M * 6; i += 256) s_ann[i] = annb[i];
    __syncthreads();

    const int a = base + tid;
    float l_npos = 0.f, l_reg = 0.f, l_dist = 0.f;
    int st = -1;  // -1 negative (incl. tail), -2 ignore, >=0 positive class
    if (a < A) {
        const float4 av = *(const float4*)(anchors + (size_t)a * 4);
        const float aw = av.z - av.x, ah = av.w - av.y;
        const float acx = av.x + 0.5f * aw, acy = av.y + 0.5f * ah;
        const float aarea = aw * ah;

        float best = -1.0f;
        int bi = 0;
        for (int m = 0; m < M; ++m) {
            const float* g = s_ann + m * 6;
            float iou = -1.0f;
            if (g[4] != -1.0f) {
                float iw = fmaxf(fminf(av.z, g[2]) - fmaxf(av.x, g[0]), 0.f);
                float ih = fmaxf(fminf(av.w, g[3]) - fmaxf(av.y, g[1]), 0.f);
                float inter = iw * ih;
                float area = (g[2] - g[0]) * (g[3] - g[1]);
                float ua = fmaxf(aarea + area - inter, 1e-8f);
                iou = inter / ua;
            }
            if (iou > best) { best = iou; bi = m; }  // strict > => first max (jnp.argmax)
        }

        if (best >= 0.5f) {
            const float* g = s_ann + bi * 6;
            st = (int)g[4];
            l_npos = 1.f;
            const float4 rv = *(const float4*)(reg + ((size_t)b * A + a) * 4);
            const float gwr = g[2] - g[0], ghr = g[3] - g[1];
            const float gcx = g[0] + 0.5f * gwr, gcy = g[1] + 0.5f * ghr;
            const float gw = fmaxf(gwr, 1.f), gh = fmaxf(ghr, 1.f);
            const float t0 = ((gcx - acx) / aw) / 0.1f;
            const float t1 = ((gcy - acy) / ah) / 0.1f;
            const float t2 = __logf(gw / aw) / 0.2f;
            const float t3 = __logf(gh / ah) / 0.2f;
            l_reg = smooth_l1(fabsf(t0 - rv.x)) + smooth_l1(fabsf(t1 - rv.y)) +
                    smooth_l1(fabsf(t2 - rv.z)) + smooth_l1(fabsf(t3 - rv.w));
            const float dv = dist[(size_t)b * A + a];
            const float dd = fabsf(dv - g[5]);
            l_dist = dd <= 0.5f ? 0.5f * dd * dd : 0.5f * (dd - 0.25f);
        } else if (best >= 0.4f) {
            st = -2;
        }
    }

    // corrections for rare non-negative anchors (wave-cooperative)
    const v4f* __restrict__ clsb = (const v4f*)(cls + ((size_t)b * A + base) * (CPA * 4));
    float corr = 0.f;
    unsigned long long mask = __ballot(st != -1);
    const int wbase = tid & ~63;
    while (mask) {
        const int bit = (int)__ffsll(mask) - 1;
        mask &= mask - 1;
        const int sst = __shfl(st, bit);
        const int la = wbase + bit;  // local anchor index within block
        if (sst == -2) {
            // ignored anchor: remove its entire streamed row
            float part = 0.f;
            if (lane < CPA) {
                const v4f cv = clsb[(size_t)la * CPA + lane];
                part = proc4(cv, part);
            }
            part = wave_reduce_sum(part);
            if (lane == 0) corr += LN2_075 * part;  // streamed scale is -LN2_075
        } else if (lane == 0) {
            // positive anchor: swap its labeled element from neg-form to pos-form
            const float cr = cls[((size_t)b * A + base + la) * (CPA * 4) + sst];
            const float c = fminf(fmaxf(cr, 1e-4f), 1.0f - 1e-4f);
            const float om = 1.0f - c;
            corr += LN2_075 * (c * c * __log2f(om))   // remove streamed negative term
                    + 0.25f * om * om * (-__logf(c)); // add focal positive term
        }
    }

    __shared__ float s_red4[4][4];
    const float w0 = wave_reduce_sum(l_npos);
    const float w1 = wave_reduce_sum(corr);
    const float w2 = wave_reduce_sum(l_reg);
    const float w3 = wave_reduce_sum(l_dist);
    if (lane == 0) {
        s_red4[0][wid] = w0; s_red4[1][wid] = w1; s_red4[2][wid] = w2; s_red4[3][wid] = w3;
    }
    __syncthreads();
    if (tid == 0) {
        float4 p;
        p.x = s_red4[0][0] + s_red4[0][1] + s_red4[0][2] + s_red4[0][3];
        p.y = s_red4[1][0] + s_red4[1][1] + s_red4[1][2] + s_red4[1][3];
        p.z = s_red4[2][0] + s_red4[2][1] + s_red4[2][2] + s_red4[2][3];
        p.w = s_red4[3][0] + s_red4[3][1] + s_red4[3][2] + s_red4[3][3];
        partB[(size_t)b * nb + blk] = p;
    }
}

// One wave per batch sample; B <= 8. SBLK==0 skips partA (generic path).
__global__ void finalize_kernel(const float* __restrict__ partA,
                                const float4* __restrict__ partB,
                                float* __restrict__ out, int B, int SBLK, int nb) {
    const int lane = threadIdx.x & 63;
    const int b = threadIdx.x >> 6;
    __shared__ float s_res[8][3];
    if (b < B) {
        float sa = 0.f, np_ = 0.f, corr = 0.f, rs = 0.f, ds = 0.f;
        for (int i = lane; i < SBLK; i += 64) sa += partA[(size_t)b * SBLK + i];
        for (int i = lane; i < nb; i += 64) {
            const float4 p = partB[(size_t)b * nb + i];
            np_ += p.x; corr += p.y; rs += p.z; ds += p.w;
        }
        sa = wave_reduce_sum(sa);
        np_ = wave_reduce_sum(np_);
        corr = wave_reduce_sum(corr);
        rs = wave_reduce_sum(rs);
        ds = wave_reduce_sum(ds);
        if (lane == 0) {
            const float cls_total = fmaf(sa, -LN2_075, corr);
            const float denom = fmaxf(np_, 1.f);
            s_res[b][0] = cls_total / denom;
            s_res[b][1] = np_ > 0.f ? rs / (denom * 4.f) : 0.f;
            s_res[b][2] = np_ > 0.f ? ds / denom : 0.f;
        }
    }
    __syncthreads();
    if (threadIdx.x == 0) {
        float c = 0.f, r = 0.f, d = 0.f;
        for (int i = 0; i < B; ++i) { c += s_res[i][0]; r += s_res[i][1]; d += s_res[i][2]; }
        out[0] = c / (float)B;
        out[1] = r / (float)B;
        out[2] = d / (float)B;
    }
}

// Generic fallback for C != 80 (runtime chunks-per-anchor); writes full cls sum to partB.y.
__global__ __launch_bounds__(256) void fused_generic_kernel(
    const float* __restrict__ cls, const float* __restrict__ reg,
    const float* __restrict__ dist, const float* __restrict__ anchors,
    const float* __restrict__ ann, float4* __restrict__ partials,
    int A, int C, int M, int nb) {
    const int b = blockIdx.y;
    const int base = blockIdx.x << 8;
    const int tid = threadIdx.x;
    const int cpa = C >> 2;

    __shared__ float s_ann[64 * 6];
    __shared__ signed char s_state[256];
    const float* annb = ann + (size_t)b * M * 6;
    for (int i = tid; i < M * 6; i += 256) s_ann[i] = annb[i];
    s_state[tid] = -2;
    __syncthreads();

    const int a = base + tid;
    float l_npos = 0.f, l_reg = 0.f, l_dist = 0.f;
    if (a < A) {
        const float4 av = *(const float4*)(anchors + (size_t)a * 4);
        const float aw = av.z - av.x, ah = av.w - av.y;
        const float acx = av.x + 0.5f * aw, acy = av.y + 0.5f * ah;
        const float aarea = aw * ah;
        float best = -1.0f;
        int bi = 0;
        for (int m = 0; m < M; ++m) {
            const float* g = s_ann + m * 6;
            float iou = -1.0f;
            if (g[4] != -1.0f) {
                float iw = fmaxf(fminf(av.z, g[2]) - fmaxf(av.x, g[0]), 0.f);
                float ih = fmaxf(fminf(av.w, g[3]) - fmaxf(av.y, g[1]), 0.f);
                float inter = iw * ih;
                float area = (g[2] - g[0]) * (g[3] - g[1]);
                float ua = fmaxf(aarea + area - inter, 1e-8f);
                iou = inter / ua;
            }
            if (iou > best) { best = iou; bi = m; }
        }
        signed char st;
        if (best >= 0.5f) {
            const float* g = s_ann + bi * 6;
            st = (signed char)(int)g[4];
            l_npos = 1.f;
            const float4 rv = *(const float4*)(reg + ((size_t)b * A + a) * 4);
            const float gwr = g[2] - g[0], ghr = g[3] - g[1];
            const float gcx = g[0] + 0.5f * gwr, gcy = g[1] + 0.5f * ghr;
            const float gw = fmaxf(gwr, 1.f), gh = fmaxf(ghr, 1.f);
            const float t0 = ((gcx - acx) / aw) / 0.1f;
            const float t1 = ((gcy - acy) / ah) / 0.1f;
            const float t2 = __logf(gw / aw) / 0.2f;
            const float t3 = __logf(gh / ah) / 0.2f;
            l_reg = smooth_l1(fabsf(t0 - rv.x)) + smooth_l1(fabsf(t1 - rv.y)) +
                    smooth_l1(fabsf(t2 - rv.z)) + smooth_l1(fabsf(t3 - rv.w));
            const float dv = dist[(size_t)b * A + a];
            const float dd = fabsf(dv - g[5]);
            l_dist = dd <= 0.5f ? 0.5f * dd * dd : 0.5f * (dd - 0.25f);
        } else if (best < 0.4f) {
            st = -1;
        } else {
            st = -2;
        }
        s_state[tid] = st;
    }
    __syncthreads();

    const float4* __restrict__ clsb = (const float4*)(cls + ((size_t)b * A + base) * C);
    int a_local = tid / cpa;
    int cc = tid % cpa;
    const int dA = 256 / cpa;
    const int dC = 256 % cpa;
    float lsum = 0.f;
    for (int k = 0; k < cpa; ++k) {
        const int st = s_state[a_local];
        if (st != -2) {
            const float4 cv = clsb[k * 256 + tid];
            const int c0 = cc << 2;
#pragma unroll
            for (int j = 0; j < 4; ++j) {
                float c = j == 0 ? cv.x : j == 1 ? cv.y : j == 2 ? cv.z : cv.w;
                c = fminf(fmaxf(c, 1e-4f), 1.0f - 1e-4f);
                const bool ispos = (st == c0 + j);
                const float om = 1.0f - c;
                const float x = ispos ? c : om;
                const float w = ispos ? 0.25f * om * om : 0.75f * c * c;
                lsum -= w * __logf(x);
            }
        }
        a_local += dA;
        cc += dC;
        if (cc >= cpa) { cc -= cpa; ++a_local; }
    }

    __shared__ float s_red[4][4];
    const float w0 = wave_reduce_sum(l_npos);
    const float w1 = wave_reduce_sum(lsum);
    const float w2 = wave_reduce_sum(l_reg);
    const float w3 = wave_reduce_sum(l_dist);
    const int lane = tid & 63, wid = tid >> 6;
    if (lane == 0) {
        s_red[0][wid] = w0; s_red[1][wid] = w1; s_red[2][wid] = w2; s_red[3][wid] = w3;
    }
    __syncthreads();
    if (tid == 0) {
        float4 p;
        p.x = s_red[0][0] + s_red[0][1] + s_red[0][2] + s_red[0][3];
        p.y = s_red[1][0] + s_red[1][1] + s_red[1][2] + s_red[1][3];
        p.z = s_red[2][0] + s_red[2][1] + s_red[2][2] + s_red[2][3];
        p.w = s_red[3][0] + s_red[3][1] + s_red[3][2] + s_red[3][3];
        partials[(size_t)b * nb + blockIdx.x] = p;
    }
}

extern "C" void kernel_launch(void* const* d_in, const int* in_sizes, int n_in,
                              void* d_out, int out_size, void* d_ws, size_t ws_size,
                              hipStream_t stream) {
    const float* cls     = (const float*)d_in[0];
    const float* reg     = (const float*)d_in[1];
    const float* dist    = (const float*)d_in[2];
    const float* anchors = (const float*)d_in[3];
    const float* ann     = (const float*)d_in[4];

    const int A = in_sizes[3] / 4;
    const int B = in_sizes[1] / (A * 4);
    const int C = in_sizes[0] / (B * A);
    const int M = in_sizes[4] / (B * 6);
    const int nb = (A + 255) / 256;
    const int SBLK = 256;

    float* partA = (float*)d_ws;                      // B*SBLK floats (8 KB for B=8)
    float4* partB = (float4*)((char*)d_ws + 8192);    // B*nb float4

    if (C == 80) {
        dim3 g(SBLK + nb, B), blk(256);
        main_kernel<20><<<g, blk, 0, stream>>>(cls, reg, dist, anchors, ann,
                                               partA, partB, A, M, SBLK, nb);
        finalize_kernel<<<1, B * 64, 0, stream>>>(partA, partB, (float*)d_out, B, SBLK, nb);
    } else {
        dim3 g(nb, B), blk(256);
        fused_generic_kernel<<<g, blk, 0, stream>>>(cls, reg, dist, anchors, ann,
                                                    partB, A, C, M, nb);
        finalize_kernel<<<1, B * 64, 0, stream>>>(partA, partB, (float*)d_out, B, 0, nb);
    }
}

// Round 6
// 75.293 us; speedup vs baseline: 3.3335x; 1.0550x over previous
//
#include <hip/hip_runtime.h>
#include <hip/hip_bf16.h>

// Workspace layout:
//   [0, 8192)        : float partA[B][SBLK]   per-stream-block cls partial sums
//   [8192, 8192+60KB): float4 partB[B][nb]    per-assign-block {npos, corr, reg, dist}
// main kernel: blockIdx.x < SBLK  -> pure streaming reduction over cls (all-negative form)
//              blockIdx.x >= SBLK -> anchor assignment + per-thread corrections
// finalize: merge partials, write 3 outputs.

typedef float v4f __attribute__((ext_vector_type(4)));

#define LN2_075 0.51986038542f  // 0.75 * ln(2)

__device__ __forceinline__ float wave_reduce_sum(float v) {
#pragma unroll
    for (int off = 32; off > 0; off >>= 1) v += __shfl_down(v, off);
    return v;
}

__device__ __forceinline__ float smooth_l1(float d) {
    // beta = 1/9: d<=beta ? 0.5*9*d^2 : d - 0.5/9
    return d <= (1.0f / 9.0f) ? 4.5f * d * d : d - (0.5f / 9.0f);
}

__device__ __forceinline__ float proc4(v4f cv, float acc) {
#pragma unroll
    for (int j = 0; j < 4; ++j) {
        const float c = fminf(fmaxf(cv[j], 1e-4f), 1.0f - 1e-4f);
        acc = fmaf(c * c, __log2f(1.0f - c), acc);
    }
    return acc;
}

template <int CPA>  // float4 chunks per anchor = C/4
__global__ __launch_bounds__(256) void main_kernel(
    const float* __restrict__ cls, const float* __restrict__ reg,
    const float* __restrict__ dist, const float* __restrict__ anchors,
    const float* __restrict__ ann, float* __restrict__ partA,
    float4* __restrict__ partB, int A, int M, int SBLK, int nb) {
    const int b = blockIdx.y;
    const int tid = threadIdx.x;
    const int lane = tid & 63;
    const int wid = tid >> 6;

    if (blockIdx.x < SBLK) {
        // ================= STREAM ROLE: pure read-reduction =================
        const int NC4 = A * CPA;  // float4s per sample
        const v4f* __restrict__ p = (const v4f*)(cls + (size_t)b * NC4 * 4);
        const int s = SBLK << 8;
        int i = (blockIdx.x << 8) + tid;
        float acc = 0.f;
        for (; i + 3 * s < NC4; i += 4 * s) {
            const v4f a0 = p[i];
            const v4f a1 = p[i + s];
            const v4f a2 = p[i + 2 * s];
            const v4f a3 = p[i + 3 * s];
            acc = proc4(a0, acc);
            acc = proc4(a1, acc);
            acc = proc4(a2, acc);
            acc = proc4(a3, acc);
        }
        for (; i < NC4; i += s) acc = proc4(p[i], acc);

        __shared__ float s_red[4];
        acc = wave_reduce_sum(acc);
        if (lane == 0) s_red[wid] = acc;
        __syncthreads();
        if (tid == 0)
            partA[(size_t)b * SBLK + blockIdx.x] = s_red[0] + s_red[1] + s_red[2] + s_red[3];
        return;
    }

    // ================= ASSIGN ROLE: IoU assignment + corrections =================
    const int blk = blockIdx.x - SBLK;
    const int base = blk << 8;  // 256 anchors per block

    __shared__ float s_ann[64 * 6];
    const float* annb = ann + (size_t)b * M * 6;
    for (int i = tid; i < M * 6; i += 256) s_ann[i] = annb[i];
    __syncthreads();

    const int a = base + tid;
    float l_npos = 0.f, l_reg = 0.f, l_dist = 0.f;
    int st = -1;  // -1 negative (incl. tail), -2 ignore, >=0 positive class
    if (a < A) {
        const float4 av = *(const float4*)(anchors + (size_t)a * 4);
        const float aw = av.z - av.x, ah = av.w - av.y;
        const float acx = av.x + 0.5f * aw, acy = av.y + 0.5f * ah;
        const float aarea = aw * ah;

        float best = -1.0f;
        int bi = 0;
        for (int m = 0; m < M; ++m) {
            const float* g = s_ann + m * 6;
            float iou = -1.0f;
            if (g[4] != -1.0f) {
                float iw = fmaxf(fminf(av.z, g[2]) - fmaxf(av.x, g[0]), 0.f);
                float ih = fmaxf(fminf(av.w, g[3]) - fmaxf(av.y, g[1]), 0.f);
                float inter = iw * ih;
                float area = (g[2] - g[0]) * (g[3] - g[1]);
                float ua = fmaxf(aarea + area - inter, 1e-8f);
                iou = inter / ua;
            }
            if (iou > best) { best = iou; bi = m; }  // strict > => first max (jnp.argmax)
        }

        if (best >= 0.5f) {
            const float* g = s_ann + bi * 6;
            st = (int)g[4];
            l_npos = 1.f;
            const float4 rv = *(const float4*)(reg + ((size_t)b * A + a) * 4);
            const float gwr = g[2] - g[0], ghr = g[3] - g[1];
            const float gcx = g[0] + 0.5f * gwr, gcy = g[1] + 0.5f * ghr;
            const float gw = fmaxf(gwr, 1.f), gh = fmaxf(ghr, 1.f);
            const float t0 = ((gcx - acx) / aw) / 0.1f;
            const float t1 = ((gcy - acy) / ah) / 0.1f;
            const float t2 = __logf(gw / aw) / 0.2f;
            const float t3 = __logf(gh / ah) / 0.2f;
            l_reg = smooth_l1(fabsf(t0 - rv.x)) + smooth_l1(fabsf(t1 - rv.y)) +
                    smooth_l1(fabsf(t2 - rv.z)) + smooth_l1(fabsf(t3 - rv.w));
            const float dv = dist[(size_t)b * A + a];
            const float dd = fabsf(dv - g[5]);
            l_dist = dd <= 0.5f ? 0.5f * dd * dd : 0.5f * (dd - 0.25f);
        } else if (best >= 0.4f) {
            st = -2;
        }
    }

    // ---- per-thread corrections (divergent but parallel across lanes) ----
    const v4f* __restrict__ clsb = (const v4f*)(cls + ((size_t)b * A + base) * (CPA * 4));
    float corr = 0.f;
    if (st >= 0) {
        // positive anchor: swap its labeled element from neg-form to pos-form
        const float cr = cls[((size_t)b * A + a) * (CPA * 4) + st];
        const float c = fminf(fmaxf(cr, 1e-4f), 1.0f - 1e-4f);
        const float om = 1.0f - c;
        corr = LN2_075 * (c * c * __log2f(om))    // remove streamed negative term
               + 0.25f * om * om * (-__logf(c));  // add focal positive term
    } else if (st == -2) {
        // ignored anchor: remove its entire streamed row (20 independent gathers)
        float part = 0.f;
#pragma unroll
        for (int k = 0; k < CPA; ++k) part = proc4(clsb[(size_t)tid * CPA + k], part);
        corr = LN2_075 * part;  // streamed scale is -LN2_075
    }

    __shared__ float s_red4[4][4];
    const float w0 = wave_reduce_sum(l_npos);
    const float w1 = wave_reduce_sum(corr);
    const float w2 = wave_reduce_sum(l_reg);
    const float w3 = wave_reduce_sum(l_dist);
    if (lane == 0) {
        s_red4[0][wid] = w0; s_red4[1][wid] = w1; s_red4[2][wid] = w2; s_red4[3][wid] = w3;
    }
    __syncthreads();
    if (tid == 0) {
        float4 p;
        p.x = s_red4[0][0] + s_red4[0][1] + s_red4[0][2] + s_red4[0][3];
        p.y = s_red4[1][0] + s_red4[1][1] + s_red4[1][2] + s_red4[1][3];
        p.z = s_red4[2][0] + s_red4[2][1] + s_red4[2][2] + s_red4[2][3];
        p.w = s_red4[3][0] + s_red4[3][1] + s_red4[3][2] + s_red4[3][3];
        partB[(size_t)b * nb + blk] = p;
    }
}

// One wave per batch sample; B <= 8. SBLK==0 skips partA (generic path).
__global__ void finalize_kernel(const float* __restrict__ partA,
                                const float4* __restrict__ partB,
                                float* __restrict__ out, int B, int SBLK, int nb) {
    const int lane = threadIdx.x & 63;
    const int b = threadIdx.x >> 6;
    __shared__ float s_res[8][3];
    if (b < B) {
        float sa = 0.f, np_ = 0.f, corr = 0.f, rs = 0.f, ds = 0.f;
        for (int i = lane; i < SBLK; i += 64) sa += partA[(size_t)b * SBLK + i];
        for (int i = lane; i < nb; i += 64) {
            const float4 p = partB[(size_t)b * nb + i];
            np_ += p.x; corr += p.y; rs += p.z; ds += p.w;
        }
        sa = wave_reduce_sum(sa);
        np_ = wave_reduce_sum(np_);
        corr = wave_reduce_sum(corr);
        rs = wave_reduce_sum(rs);
        ds = wave_reduce_sum(ds);
        if (lane == 0) {
            const float cls_total = fmaf(sa, -LN2_075, corr);
            const float denom = fmaxf(np_, 1.f);
            s_res[b][0] = cls_total / denom;
            s_res[b][1] = np_ > 0.f ? rs / (denom * 4.f) : 0.f;
            s_res[b][2] = np_ > 0.f ? ds / denom : 0.f;
        }
    }
    __syncthreads();
    if (threadIdx.x == 0) {
        float c = 0.f, r = 0.f, d = 0.f;
        for (int i = 0; i < B; ++i) { c += s_res[i][0]; r += s_res[i][1]; d += s_res[i][2]; }
        out[0] = c / (float)B;
        out[1] = r / (float)B;
        out[2] = d / (float)B;
    }
}

// Generic fallback for C != 80 (runtime chunks-per-anchor); writes full cls sum to partB.y.
__global__ __launch_bounds__(256) void fused_generic_kernel(
    const float* __restrict__ cls, const float* __restrict__ reg,
    const float* __restrict__ dist, const float* __restrict__ anchors,
    const float* __restrict__ ann, float4* __restrict__ partials,
    int A, int C, int M, int nb) {
    const int b = blockIdx.y;
    const int base = blockIdx.x << 8;
    const int tid = threadIdx.x;
    const int cpa = C >> 2;

    __shared__ float s_ann[64 * 6];
    __shared__ signed char s_state[256];
    const float* annb = ann + (size_t)b * M * 6;
    for (int i = tid; i < M * 6; i += 256) s_ann[i] = annb[i];
    s_state[tid] = -2;
    __syncthreads();

    const int a = base + tid;
    float l_npos = 0.f, l_reg = 0.f, l_dist = 0.f;
    if (a < A) {
        const float4 av = *(const float4*)(anchors + (size_t)a * 4);
        const float aw = av.z - av.x, ah = av.w - av.y;
        const float acx = av.x + 0.5f * aw, acy = av.y + 0.5f * ah;
        const float aarea = aw * ah;
        float best = -1.0f;
        int bi = 0;
        for (int m = 0; m < M; ++m) {
            const float* g = s_ann + m * 6;
            float iou = -1.0f;
            if (g[4] != -1.0f) {
                float iw = fmaxf(fminf(av.z, g[2]) - fmaxf(av.x, g[0]), 0.f);
                float ih = fmaxf(fminf(av.w, g[3]) - fmaxf(av.y, g[1]), 0.f);
                float inter = iw * ih;
                float area = (g[2] - g[0]) * (g[3] - g[1]);
                float ua = fmaxf(aarea + area - inter, 1e-8f);
                iou = inter / ua;
            }
            if (iou > best) { best = iou; bi = m; }
        }
        signed char st;
        if (best >= 0.5f) {
            const float* g = s_ann + bi * 6;
            st = (signed char)(int)g[4];
            l_npos = 1.f;
            const float4 rv = *(const float4*)(reg + ((size_t)b * A + a) * 4);
            const float gwr = g[2] - g[0], ghr = g[3] - g[1];
            const float gcx = g[0] + 0.5f * gwr, gcy = g[1] + 0.5f * ghr;
            const float gw = fmaxf(gwr, 1.f), gh = fmaxf(ghr, 1.f);
            const float t0 = ((gcx - acx) / aw) / 0.1f;
            const float t1 = ((gcy - acy) / ah) / 0.1f;
            const float t2 = __logf(gw / aw) / 0.2f;
            const float t3 = __logf(gh / ah) / 0.2f;
            l_reg = smooth_l1(fabsf(t0 - rv.x)) + smooth_l1(fabsf(t1 - rv.y)) +
                    smooth_l1(fabsf(t2 - rv.z)) + smooth_l1(fabsf(t3 - rv.w));
            const float dv = dist[(size_t)b * A + a];
            const float dd = fabsf(dv - g[5]);
            l_dist = dd <= 0.5f ? 0.5f * dd * dd : 0.5f * (dd - 0.25f);
        } else if (best < 0.4f) {
            st = -1;
        } else {
            st = -2;
        }
        s_state[tid] = st;
    }
    __syncthreads();

    const float4* __restrict__ clsb = (const float4*)(cls + ((size_t)b * A + base) * C);
    int a_local = tid / cpa;
    int cc = tid % cpa;
    const int dA = 256 / cpa;
    const int dC = 256 % cpa;
    float lsum = 0.f;
    for (int k = 0; k < cpa; ++k) {
        const int st = s_state[a_local];
        if (st != -2) {
            const float4 cv = clsb[k * 256 + tid];
            const int c0 = cc << 2;
#pragma unroll
            for (int j = 0; j < 4; ++j) {
                float c = j == 0 ? cv.x : j == 1 ? cv.y : j == 2 ? cv.z : cv.w;
                c = fminf(fmaxf(c, 1e-4f), 1.0f - 1e-4f);
                const bool ispos = (st == c0 + j);
                const float om = 1.0f - c;
                const float x = ispos ? c : om;
                const float w = ispos ? 0.25f * om * om : 0.75f * c * c;
                lsum -= w * __logf(x);
            }
        }
        a_local += dA;
        cc += dC;
        if (cc >= cpa) { cc -= cpa; ++a_local; }
    }

    __shared__ float s_red[4][4];
    const float w0 = wave_reduce_sum(l_npos);
    const float w1 = wave_reduce_sum(lsum);
    const float w2 = wave_reduce_sum(l_reg);
    const float w3 = wave_reduce_sum(l_dist);
    const int lane = tid & 63, wid = tid >> 6;
    if (lane == 0) {
        s_red[0][wid] = w0; s_red[1][wid] = w1; s_red[2][wid] = w2; s_red[3][wid] = w3;
    }
    __syncthreads();
    if (tid == 0) {
        float4 p;
        p.x = s_red[0][0] + s_red[0][1] + s_red[0][2] + s_red[0][3];
        p.y = s_red[1][0] + s_red[1][1] + s_red[1][2] + s_red[1][3];
        p.z = s_red[2][0] + s_red[2][1] + s_red[2][2] + s_red[2][3];
        p.w = s_red[3][0] + s_red[3][1] + s_red[3][2] + s_red[3][3];
        partials[(size_t)b * nb + blockIdx.x] = p;
    }
}

extern "C" void kernel_launch(void* const* d_in, const int* in_sizes, int n_in,
                              void* d_out, int out_size, void* d_ws, size_t ws_size,
                              hipStream_t stream) {
    const float* cls     = (const float*)d_in[0];
    const float* reg     = (const float*)d_in[1];
    const float* dist    = (const float*)d_in[2];
    const float* anchors = (const float*)d_in[3];
    const float* ann     = (const float*)d_in[4];

    const int A = in_sizes[3] / 4;
    const int B = in_sizes[1] / (A * 4);
    const int C = in_sizes[0] / (B * A);
    const int M = in_sizes[4] / (B * 6);
    const int nb = (A + 255) / 256;
    const int SBLK = 256;

    float* partA = (float*)d_ws;                      // B*SBLK floats (8 KB for B=8)
    float4* partB = (float4*)((char*)d_ws + 8192);    // B*nb float4

    if (C == 80) {
        dim3 g(SBLK + nb, B), blk(256);
        main_kernel<20><<<g, blk, 0, stream>>>(cls, reg, dist, anchors, ann,
                                               partA, partB, A, M, SBLK, nb);
        finalize_kernel<<<1, B * 64, 0, stream>>>(partA, partB, (float*)d_out, B, SBLK, nb);
    } else {
        dim3 g(nb, B), blk(256);
        fused_generic_kernel<<<g, blk, 0, stream>>>(cls, reg, dist, anchors, ann,
                                                    partB, A, C, M, nb);
        finalize_kernel<<<1, B * 64, 0, stream>>>(partA, partB, (float*)d_out, B, 0, nb);
    }
}

// Round 7
// 73.981 us; speedup vs baseline: 3.3926x; 1.0177x over previous
//
#include <hip/hip_runtime.h>
#include <hip/hip_bf16.h>

// Workspace layout:
//   [0, 8192)        : float partA[B][SBLK]   per-stream-block cls partial sums
//   [8192, 8192+60KB): float4 partB[B][nb]    per-assign-block {npos, corr, reg, dist}
// main kernel: blockIdx.x < nb  -> anchor assignment + per-thread corrections (dispatched first)
//              blockIdx.x >= nb -> contiguous-chunk streaming reduction over cls (all-negative form)
// finalize: merge partials, write 3 outputs.

typedef float v4f __attribute__((ext_vector_type(4)));

#define LN2_075 0.51986038542f  // 0.75 * ln(2)

__device__ __forceinline__ float wave_reduce_sum(float v) {
#pragma unroll
    for (int off = 32; off > 0; off >>= 1) v += __shfl_down(v, off);
    return v;
}

__device__ __forceinline__ float smooth_l1(float d) {
    // beta = 1/9: d<=beta ? 0.5*9*d^2 : d - 0.5/9
    return d <= (1.0f / 9.0f) ? 4.5f * d * d : d - (0.5f / 9.0f);
}

// Streamed negative-form accumulator: c^2*log2(1-c) with only the upper clamp.
// (Lower clamp max(c,1e-4) omitted: |error| < 2e-12/element; cls >= 0 always.)
__device__ __forceinline__ float proc4t(v4f cv, float acc) {
#pragma unroll
    for (int j = 0; j < 4; ++j) {
        const float c = fminf(cv[j], 1.0f - 1e-4f);
        acc = fmaf(c * c, __log2f(1.0f - c), acc);
    }
    return acc;
}

template <int CPA>  // float4 chunks per anchor = C/4
__global__ __launch_bounds__(256) void main_kernel(
    const float* __restrict__ cls, const float* __restrict__ reg,
    const float* __restrict__ dist, const float* __restrict__ anchors,
    const float* __restrict__ ann, float* __restrict__ partA,
    float4* __restrict__ partB, int A, int M, int SBLK, int nb) {
    const int b = blockIdx.y;
    const int tid = threadIdx.x;
    const int lane = tid & 63;
    const int wid = tid >> 6;

    if (blockIdx.x >= nb) {
        // ========== STREAM ROLE: contiguous-chunk read-reduction ==========
        const int sb = blockIdx.x - nb;  // 0..SBLK-1
        const int NC4 = A * CPA;         // float4s per sample
        const int chunk = (NC4 + SBLK - 1) / SBLK;
        const int start = sb * chunk;
        const int end = min(start + chunk, NC4);
        const v4f* __restrict__ p = (const v4f*)(cls + (size_t)b * NC4 * 4);

        float acc0 = 0.f, acc1 = 0.f;
        int i = start + tid;
        for (; i + 768 < end; i += 1024) {
            const v4f a0 = p[i];
            const v4f a1 = p[i + 256];
            const v4f a2 = p[i + 512];
            const v4f a3 = p[i + 768];
            acc0 = proc4t(a0, acc0);
            acc1 = proc4t(a1, acc1);
            acc0 = proc4t(a2, acc0);
            acc1 = proc4t(a3, acc1);
        }
        for (; i < end; i += 256) acc0 = proc4t(p[i], acc0);

        __shared__ float s_red[4];
        float acc = wave_reduce_sum(acc0 + acc1);
        if (lane == 0) s_red[wid] = acc;
        __syncthreads();
        if (tid == 0)
            partA[(size_t)b * SBLK + sb] = s_red[0] + s_red[1] + s_red[2] + s_red[3];
        return;
    }

    // ========== ASSIGN ROLE: IoU assignment + corrections ==========
    const int blk = blockIdx.x;
    const int base = blk << 8;  // 256 anchors per block

    __shared__ float s_ann[64 * 6];
    const float* annb = ann + (size_t)b * M * 6;
    for (int i = tid; i < M * 6; i += 256) s_ann[i] = annb[i];
    __syncthreads();

    const int a = base + tid;
    float l_npos = 0.f, l_reg = 0.f, l_dist = 0.f;
    int st = -1;  // -1 negative (incl. tail), -2 ignore, >=0 positive class
    if (a < A) {
        const float4 av = *(const float4*)(anchors + (size_t)a * 4);
        const float aw = av.z - av.x, ah = av.w - av.y;
        const float acx = av.x + 0.5f * aw, acy = av.y + 0.5f * ah;
        const float aarea = aw * ah;

        float best = -1.0f;
        int bi = 0;
        for (int m = 0; m < M; ++m) {
            const float* g = s_ann + m * 6;
            float iou = -1.0f;
            if (g[4] != -1.0f) {
                float iw = fmaxf(fminf(av.z, g[2]) - fmaxf(av.x, g[0]), 0.f);
                float ih = fmaxf(fminf(av.w, g[3]) - fmaxf(av.y, g[1]), 0.f);
                float inter = iw * ih;
                float area = (g[2] - g[0]) * (g[3] - g[1]);
                float ua = fmaxf(aarea + area - inter, 1e-8f);
                iou = inter / ua;
            }
            if (iou > best) { best = iou; bi = m; }  // strict > => first max (jnp.argmax)
        }

        if (best >= 0.5f) {
            const float* g = s_ann + bi * 6;
            st = (int)g[4];
            l_npos = 1.f;
            const float4 rv = *(const float4*)(reg + ((size_t)b * A + a) * 4);
            const float gwr = g[2] - g[0], ghr = g[3] - g[1];
            const float gcx = g[0] + 0.5f * gwr, gcy = g[1] + 0.5f * ghr;
            const float gw = fmaxf(gwr, 1.f), gh = fmaxf(ghr, 1.f);
            const float t0 = ((gcx - acx) / aw) / 0.1f;
            const float t1 = ((gcy - acy) / ah) / 0.1f;
            const float t2 = __logf(gw / aw) / 0.2f;
            const float t3 = __logf(gh / ah) / 0.2f;
            l_reg = smooth_l1(fabsf(t0 - rv.x)) + smooth_l1(fabsf(t1 - rv.y)) +
                    smooth_l1(fabsf(t2 - rv.z)) + smooth_l1(fabsf(t3 - rv.w));
            const float dv = dist[(size_t)b * A + a];
            const float dd = fabsf(dv - g[5]);
            l_dist = dd <= 0.5f ? 0.5f * dd * dd : 0.5f * (dd - 0.25f);
        } else if (best >= 0.4f) {
            st = -2;
        }
    }

    // ---- per-thread corrections (divergent but parallel across lanes) ----
    const v4f* __restrict__ clsb = (const v4f*)(cls + ((size_t)b * A + base) * (CPA * 4));
    float corr = 0.f;
    if (st >= 0) {
        // positive anchor: swap its labeled element from neg-form to pos-form
        const float cr = cls[((size_t)b * A + a) * (CPA * 4) + st];
        const float ct = fminf(cr, 1.0f - 1e-4f);            // matches streamed form
        const float c = fminf(fmaxf(cr, 1e-4f), 1.0f - 1e-4f);  // reference clamp
        const float om = 1.0f - c;
        corr = LN2_075 * (ct * ct * __log2f(1.0f - ct))  // remove streamed negative term
               + 0.25f * om * om * (-__logf(c));         // add focal positive term
    } else if (st == -2) {
        // ignored anchor: remove its entire streamed row (CPA independent gathers)
        float part = 0.f;
#pragma unroll
        for (int k = 0; k < CPA; ++k) part = proc4t(clsb[(size_t)tid * CPA + k], part);
        corr = LN2_075 * part;  // streamed scale is -LN2_075
    }

    __shared__ float s_red4[4][4];
    const float w0 = wave_reduce_sum(l_npos);
    const float w1 = wave_reduce_sum(corr);
    const float w2 = wave_reduce_sum(l_reg);
    const float w3 = wave_reduce_sum(l_dist);
    if (lane == 0) {
        s_red4[0][wid] = w0; s_red4[1][wid] = w1; s_red4[2][wid] = w2; s_red4[3][wid] = w3;
    }
    __syncthreads();
    if (tid == 0) {
        float4 p;
        p.x = s_red4[0][0] + s_red4[0][1] + s_red4[0][2] + s_red4[0][3];
        p.y = s_red4[1][0] + s_red4[1][1] + s_red4[1][2] + s_red4[1][3];
        p.z = s_red4[2][0] + s_red4[2][1] + s_red4[2][2] + s_red4[2][3];
        p.w = s_red4[3][0] + s_red4[3][1] + s_red4[3][2] + s_red4[3][3];
        partB[(size_t)b * nb + blk] = p;
    }
}

// One wave per batch sample; B <= 8. SBLK==0 skips partA (generic path).
__global__ void finalize_kernel(const float* __restrict__ partA,
                                const float4* __restrict__ partB,
                                float* __restrict__ out, int B, int SBLK, int nb) {
    const int lane = threadIdx.x & 63;
    const int b = threadIdx.x >> 6;
    __shared__ float s_res[8][3];
    if (b < B) {
        float sa = 0.f, np_ = 0.f, corr = 0.f, rs = 0.f, ds = 0.f;
        for (int i = lane; i < SBLK; i += 64) sa += partA[(size_t)b * SBLK + i];
        for (int i = lane; i < nb; i += 64) {
            const float4 p = partB[(size_t)b * nb + i];
            np_ += p.x; corr += p.y; rs += p.z; ds += p.w;
        }
        sa = wave_reduce_sum(sa);
        np_ = wave_reduce_sum(np_);
        corr = wave_reduce_sum(corr);
        rs = wave_reduce_sum(rs);
        ds = wave_reduce_sum(ds);
        if (lane == 0) {
            const float cls_total = fmaf(sa, -LN2_075, corr);
            const float denom = fmaxf(np_, 1.f);
            s_res[b][0] = cls_total / denom;
            s_res[b][1] = np_ > 0.f ? rs / (denom * 4.f) : 0.f;
            s_res[b][2] = np_ > 0.f ? ds / denom : 0.f;
        }
    }
    __syncthreads();
    if (threadIdx.x == 0) {
        float c = 0.f, r = 0.f, d = 0.f;
        for (int i = 0; i < B; ++i) { c += s_res[i][0]; r += s_res[i][1]; d += s_res[i][2]; }
        out[0] = c / (float)B;
        out[1] = r / (float)B;
        out[2] = d / (float)B;
    }
}

// Generic fallback for C != 80 (runtime chunks-per-anchor); writes full cls sum to partB.y.
__global__ __launch_bounds__(256) void fused_generic_kernel(
    const float* __restrict__ cls, const float* __restrict__ reg,
    const float* __restrict__ dist, const float* __restrict__ anchors,
    const float* __restrict__ ann, float4* __restrict__ partials,
    int A, int C, int M, int nb) {
    const int b = blockIdx.y;
    const int base = blockIdx.x << 8;
    const int tid = threadIdx.x;
    const int cpa = C >> 2;

    __shared__ float s_ann[64 * 6];
    __shared__ signed char s_state[256];
    const float* annb = ann + (size_t)b * M * 6;
    for (int i = tid; i < M * 6; i += 256) s_ann[i] = annb[i];
    s_state[tid] = -2;
    __syncthreads();

    const int a = base + tid;
    float l_npos = 0.f, l_reg = 0.f, l_dist = 0.f;
    if (a < A) {
        const float4 av = *(const float4*)(anchors + (size_t)a * 4);
        const float aw = av.z - av.x, ah = av.w - av.y;
        const float acx = av.x + 0.5f * aw, acy = av.y + 0.5f * ah;
        const float aarea = aw * ah;
        float best = -1.0f;
        int bi = 0;
        for (int m = 0; m < M; ++m) {
            const float* g = s_ann + m * 6;
            float iou = -1.0f;
            if (g[4] != -1.0f) {
                float iw = fmaxf(fminf(av.z, g[2]) - fmaxf(av.x, g[0]), 0.f);
                float ih = fmaxf(fminf(av.w, g[3]) - fmaxf(av.y, g[1]), 0.f);
                float inter = iw * ih;
                float area = (g[2] - g[0]) * (g[3] - g[1]);
                float ua = fmaxf(aarea + area - inter, 1e-8f);
                iou = inter / ua;
            }
            if (iou > best) { best = iou; bi = m; }
        }
        signed char st;
        if (best >= 0.5f) {
            const float* g = s_ann + bi * 6;
            st = (signed char)(int)g[4];
            l_npos = 1.f;
            const float4 rv = *(const float4*)(reg + ((size_t)b * A + a) * 4);
            const float gwr = g[2] - g[0], ghr = g[3] - g[1];
            const float gcx = g[0] + 0.5f * gwr, gcy = g[1] + 0.5f * ghr;
            const float gw = fmaxf(gwr, 1.f), gh = fmaxf(ghr, 1.f);
            const float t0 = ((gcx - acx) / aw) / 0.1f;
            const float t1 = ((gcy - acy) / ah) / 0.1f;
            const float t2 = __logf(gw / aw) / 0.2f;
            const float t3 = __logf(gh / ah) / 0.2f;
            l_reg = smooth_l1(fabsf(t0 - rv.x)) + smooth_l1(fabsf(t1 - rv.y)) +
                    smooth_l1(fabsf(t2 - rv.z)) + smooth_l1(fabsf(t3 - rv.w));
            const float dv = dist[(size_t)b * A + a];
            const float dd = fabsf(dv - g[5]);
            l_dist = dd <= 0.5f ? 0.5f * dd * dd : 0.5f * (dd - 0.25f);
        } else if (best < 0.4f) {
            st = -1;
        } else {
            st = -2;
        }
        s_state[tid] = st;
    }
    __syncthreads();

    const float4* __restrict__ clsb = (const float4*)(cls + ((size_t)b * A + base) * C);
    int a_local = tid / cpa;
    int cc = tid % cpa;
    const int dA = 256 / cpa;
    const int dC = 256 % cpa;
    float lsum = 0.f;
    for (int k = 0; k < cpa; ++k) {
        const int st = s_state[a_local];
        if (st != -2) {
            const float4 cv = clsb[k * 256 + tid];
            const int c0 = cc << 2;
#pragma unroll
            for (int j = 0; j < 4; ++j) {
                float c = j == 0 ? cv.x : j == 1 ? cv.y : j == 2 ? cv.z : cv.w;
                c = fminf(fmaxf(c, 1e-4f), 1.0f - 1e-4f);
                const bool ispos = (st == c0 + j);
                const float om = 1.0f - c;
                const float x = ispos ? c : om;
                const float w = ispos ? 0.25f * om * om : 0.75f * c * c;
                lsum -= w * __logf(x);
            }
        }
        a_local += dA;
        cc += dC;
        if (cc >= cpa) { cc -= cpa; ++a_local; }
    }

    __shared__ float s_red[4][4];
    const float w0 = wave_reduce_sum(l_npos);
    const float w1 = wave_reduce_sum(lsum);
    const float w2 = wave_reduce_sum(l_reg);
    const float w3 = wave_reduce_sum(l_dist);
    const int lane = tid & 63, wid = tid >> 6;
    if (lane == 0) {
        s_red[0][wid] = w0; s_red[1][wid] = w1; s_red[2][wid] = w2; s_red[3][wid] = w3;
    }
    __syncthreads();
    if (tid == 0) {
        float4 p;
        p.x = s_red[0][0] + s_red[0][1] + s_red[0][2] + s_red[0][3];
        p.y = s_red[1][0] + s_red[1][1] + s_red[1][2] + s_red[1][3];
        p.z = s_red[2][0] + s_red[2][1] + s_red[2][2] + s_red[2][3];
        p.w = s_red[3][0] + s_red[3][1] + s_red[3][2] + s_red[3][3];
        partials[(size_t)b * nb + blockIdx.x] = p;
    }
}

extern "C" void kernel_launch(void* const* d_in, const int* in_sizes, int n_in,
                              void* d_out, int out_size, void* d_ws, size_t ws_size,
                              hipStream_t stream) {
    const float* cls     = (const float*)d_in[0];
    const float* reg     = (const float*)d_in[1];
    const float* dist    = (const float*)d_in[2];
    const float* anchors = (const float*)d_in[3];
    const float* ann     = (const float*)d_in[4];

    const int A = in_sizes[3] / 4;
    const int B = in_sizes[1] / (A * 4);
    const int C = in_sizes[0] / (B * A);
    const int M = in_sizes[4] / (B * 6);
    const int nb = (A + 255) / 256;
    const int SBLK = 256;

    float* partA = (float*)d_ws;                      // B*SBLK floats (8 KB for B=8)
    float4* partB = (float4*)((char*)d_ws + 8192);    // B*nb float4

    if (C == 80) {
        dim3 g(nb + SBLK, B), blk(256);
        main_kernel<20><<<g, blk, 0, stream>>>(cls, reg, dist, anchors, ann,
                                               partA, partB, A, M, SBLK, nb);
        finalize_kernel<<<1, B * 64, 0, stream>>>(partA, partB, (float*)d_out, B, SBLK, nb);
    } else {
        dim3 g(nb, B), blk(256);
        fused_generic_kernel<<<g, blk, 0, stream>>>(cls, reg, dist, anchors, ann,
                                                    partB, A, C, M, nb);
        finalize_kernel<<<1, B * 64, 0, stream>>>(partA, partB, (float*)d_out, B, 0, nb);
    }
}